// Round 2
// baseline (190.344 us; speedup 1.0000x reference)
//
#include <hip/hip_runtime.h>
#include <math.h>

// Problem geometry: seg_out/logits (2,4,128,128,128) f32, y (2,1,128,128,128) i32,
// calib (20,4) f32, weight scalar int. Output: 1 f32 scalar.
#define VB 2097152            // voxels per (batch, channel) = 128^3
#define QB (VB / 4)           // float4 quads per (batch, channel)
#define NBINS 20

// Workspace layout (as 32-bit words):
//   [0..39]    float acc[2][5][4]  : b, quantity {Sp, Spt1, Cnt1, St2, Spt2}, channel
//   [40..119]  uint  bins[2][2][20]: class (1,2), kind {true, total}, bin
#define WS_WORDS 120

// Privatized LDS histogram: 32 copies, stride 81 words.
// 81 % 32 == 17 (odd, coprime with 32) => for a fixed bin index, the 32
// copies live on 32 distinct banks; within a wave copy = lane&31 gives at
// most 2 lanes per copy (2-way aliasing is free on gfx950).
#define HCOPIES 32
#define HSTRIDE 81

__device__ __forceinline__ float sel(const float4 v, int j) {
    return j == 0 ? v.x : (j == 1 ? v.y : (j == 2 ? v.z : v.w));
}
__device__ __forceinline__ int seli(const int4 v, int j) {
    return j == 0 ? v.x : (j == 1 ? v.y : (j == 2 ? v.z : v.w));
}

__global__ void zero_ws_k(float* __restrict__ ws) {
    int i = blockIdx.x * blockDim.x + threadIdx.x;
    if (i < WS_WORDS) ws[i] = 0.0f;   // zero bits also zero the uint region
}

__global__ __launch_bounds__(256) void hybrid_main_k(
        const float* __restrict__ seg, const float* __restrict__ logits,
        const int* __restrict__ y, const int* __restrict__ wt,
        float* __restrict__ ws)
{
    const int b   = blockIdx.x & 1;       // interleave batches across XCDs
    const int blk = blockIdx.x >> 1;      // 0..1023
    const int tid = threadIdx.x;

    __shared__ unsigned int shb[HCOPIES * HSTRIDE];   // 10368 B
    __shared__ float shred[20][4];

    for (int i = tid; i < HCOPIES * HSTRIDE; i += 256) shb[i] = 0u;
    __syncthreads();

    // weight==1 => (1-w)*L2 == 0 exactly; skip the logits stream (uniform branch,
    // deterministic across calls since inputs are restored each launch).
    const bool need2 = (wt[0] != 1);

    const float4* s0 = (const float4*)seg + (size_t)(b * 4 + 0) * QB;
    const float4* s1 = (const float4*)seg + (size_t)(b * 4 + 1) * QB;
    const float4* s2 = (const float4*)seg + (size_t)(b * 4 + 2) * QB;
    const float4* s3 = (const float4*)seg + (size_t)(b * 4 + 3) * QB;
    const float4* l0 = (const float4*)logits + (size_t)(b * 4 + 0) * QB;
    const float4* l1 = (const float4*)logits + (size_t)(b * 4 + 1) * QB;
    const float4* l2 = (const float4*)logits + (size_t)(b * 4 + 2) * QB;
    const float4* l3 = (const float4*)logits + (size_t)(b * 4 + 3) * QB;
    const int4*   yq = (const int4*)y + (size_t)b * QB;

    // acc[0..3]=Sp, [4..7]=Spt1(one-hot), [8..11]=Cnt1(as float, exact<2^24),
    // [12..15]=St2(sigmoid), [16..19]=Spt2
    float acc[20];
    #pragma unroll
    for (int k = 0; k < 20; ++k) acc[k] = 0.0f;

    const float INV_STEP = 20.0f / (1.0f + 1e-8f);  // searchsorted(linspace(0,1+1e-8,21),'right')-1
    const int hbase = (tid & 31) * HSTRIDE;

    for (int q = blk * 256 + tid; q < QB; q += 1024 * 256) {
        const int4   yv = yq[q];
        const float4 p0 = s0[q], p1 = s1[q], p2 = s2[q], p3 = s3[q];
        float4 g0 = {0,0,0,0}, g1 = {0,0,0,0}, g2 = {0,0,0,0}, g3 = {0,0,0,0};
        if (need2) { g0 = l0[q]; g1 = l1[q]; g2 = l2[q]; g3 = l3[q]; }

        #pragma unroll
        for (int j = 0; j < 4; ++j) {
            const float pv0 = sel(p0, j), pv1 = sel(p1, j), pv2 = sel(p2, j), pv3 = sel(p3, j);
            const int yj = seli(yv, j);

            acc[0] += pv0; acc[1] += pv1; acc[2] += pv2; acc[3] += pv3;
            acc[4] += (yj == 0) ? pv0 : 0.0f;
            acc[5] += (yj == 1) ? pv1 : 0.0f;
            acc[6] += (yj == 2) ? pv2 : 0.0f;
            acc[7] += (yj == 3) ? pv3 : 0.0f;
            acc[8]  += (yj == 0) ? 1.0f : 0.0f;
            acc[9]  += (yj == 1) ? 1.0f : 0.0f;
            acc[10] += (yj == 2) ? 1.0f : 0.0f;
            acc[11] += (yj == 3) ? 1.0f : 0.0f;

            if (need2) {
                const float gv0 = sel(g0, j), gv1 = sel(g1, j), gv2 = sel(g2, j), gv3 = sel(g3, j);
                const float sg0 = __fdividef(1.0f, 1.0f + __expf(-gv0));
                const float sg1 = __fdividef(1.0f, 1.0f + __expf(-gv1));
                const float sg2 = __fdividef(1.0f, 1.0f + __expf(-gv2));
                const float sg3 = __fdividef(1.0f, 1.0f + __expf(-gv3));
                acc[12] += sg0; acc[13] += sg1; acc[14] += sg2; acc[15] += sg3;
                acc[16] += pv0 * sg0; acc[17] += pv1 * sg1;
                acc[18] += pv2 * sg2; acc[19] += pv3 * sg3;
            }

            // softmax over channels (matches jax.nn.softmax: exp(x - max)/sum)
            const float mx = fmaxf(fmaxf(pv0, pv1), fmaxf(pv2, pv3));
            const float e0 = __expf(pv0 - mx), e1 = __expf(pv1 - mx);
            const float e2 = __expf(pv2 - mx), e3 = __expf(pv3 - mx);
            const float rinv = __frcp_rn((e0 + e1) + (e2 + e3));
            const float pr1 = e1 * rinv;
            const float pr2 = e2 * rinv;
            int b1 = (int)(pr1 * INV_STEP); if (b1 > 19) b1 = 19;
            int b2 = (int)(pr2 * INV_STEP); if (b2 > 19) b2 = 19;
            atomicAdd(&shb[hbase + 20 + b1], 1u);              // class-1 total
            atomicAdd(&shb[hbase + 60 + b2], 1u);              // class-2 total
            if (yj == 1) atomicAdd(&shb[hbase +  0 + b1], 1u); // class-1 true
            if (yj == 2) atomicAdd(&shb[hbase + 40 + b2], 1u); // class-2 true
        }
    }

    // wave(64) shuffle reduce each of the 20 accumulators
    #pragma unroll
    for (int k = 0; k < 20; ++k) {
        float v = acc[k];
        #pragma unroll
        for (int off = 32; off > 0; off >>= 1) v += __shfl_xor(v, off, 64);
        acc[k] = v;
    }
    const int wave = tid >> 6, lane = tid & 63;
    if (lane == 0) {
        #pragma unroll
        for (int k = 0; k < 20; ++k) shred[k][wave] = acc[k];
    }
    __syncthreads();
    if (tid < 20) {
        float t = shred[tid][0] + shred[tid][1] + shred[tid][2] + shred[tid][3];
        atomicAdd(&ws[b * 20 + tid], t);
    }
    if (tid < 80) {
        unsigned int v = 0;
        #pragma unroll
        for (int c = 0; c < HCOPIES; ++c) v += shb[c * HSTRIDE + tid];
        if (v) atomicAdd((unsigned int*)ws + 40 + tid, v);
    }
}

__device__ __forceinline__ float fsigmoid(float x) {
    return __fdividef(1.0f, 1.0f + __expf(-x));
}

__device__ double dice_term(const double Sp[2], const double St[2], const double Spt[2],
                            double w0, double w1)
{
    const double sumP = Sp[0] + Sp[1], sumT = St[0] + St[1];
    const double u1 = sumP + sumT;
    const double u0 = (2.0 * (double)VB - sumP) + (2.0 * (double)VB - sumT);
    const double uni = w0 * u0 + w1 * u1;
    double dsum = 0.0;
    for (int b = 0; b < 2; ++b) {
        const double i1 = Spt[b];
        const double i0 = (double)VB - Sp[b] - St[b] + Spt[b];
        const double inter = w0 * i0 + w1 * i1;
        double dice = (2.0 * inter + 1.0) / (uni + 1.0);
        if (isnan(dice)) dice = 1.0;
        dsum += dice;
    }
    return 1.0 - 0.5 * dsum;
}

__global__ void finalize_k(const float* __restrict__ ws,
                           const float* __restrict__ calib,
                           const int* __restrict__ wt,
                           float* __restrict__ out)
{
    const int t = threadIdx.x;

    // ECE terms in parallel: lanes 0..39 each handle one (class, bin) cell.
    const unsigned int* bins = (const unsigned int*)ws + 40;
    float term = 0.0f;
    if (t < 40) {
        const int cc = t / NBINS;        // 0 -> class 1, 1 -> class 2
        const int k  = t % NBINS;
        const float bt   = fsigmoid((float)bins[cc * 40 + k]);
        const float btot = fsigmoid((float)bins[cc * 40 + 20 + k]);
        const float cal  = fsigmoid(calib[k * 4 + (cc + 1)]);
        const float d = cal - __fdividef(bt, btot);
        term = d * d;
    }
    #pragma unroll
    for (int off = 32; off > 0; off >>= 1) term += __shfl_xor(term, off, 64);
    // term on lane 0 now = sum of all 40 cells; ece = sum / 20

    if (t == 0) {
        const double means[4] = {0.03, 0.02, 0.01, 0.01};
        double L1 = 0.0, L2 = 0.0;
        for (int c = 0; c < 4; ++c) {
            const double mean = means[c];
            const double w1 = 1.0 / (mean * mean);
            const double w0 = 1.0 / ((1.0 - mean) * (1.0 - mean));
            double Sp[2], Spt1[2], C1[2], St2[2], Spt2[2];
            for (int b = 0; b < 2; ++b) {
                Sp[b]   = (double)ws[b * 20 + 0 + c];
                Spt1[b] = (double)ws[b * 20 + 4 + c];
                C1[b]   = (double)ws[b * 20 + 8 + c];
                St2[b]  = (double)ws[b * 20 + 12 + c];
                Spt2[b] = (double)ws[b * 20 + 16 + c];
            }
            L1 += dice_term(Sp, C1, Spt1, w0, w1);
            L2 += dice_term(Sp, St2, Spt2, w0, w1);
        }
        L1 *= 0.2; L2 *= 0.2;   // sum of 4 channel losses / 5.0
        const double w = (double)wt[0];
        const double ece = (double)term / (double)NBINS;
        out[0] = (float)(w * L1 + (1.0 - w) * L2 + ece);
    }
}

extern "C" void kernel_launch(void* const* d_in, const int* in_sizes, int n_in,
                              void* d_out, int out_size, void* d_ws, size_t ws_size,
                              hipStream_t stream)
{
    const float* seg    = (const float*)d_in[0];
    const float* calib  = (const float*)d_in[1];
    const float* logits = (const float*)d_in[2];
    const int*   y      = (const int*)d_in[3];
    const int*   wt     = (const int*)d_in[4];
    float* ws  = (float*)d_ws;
    float* out = (float*)d_out;

    hipLaunchKernelGGL(zero_ws_k, dim3(1), dim3(128), 0, stream, ws);
    hipLaunchKernelGGL(hybrid_main_k, dim3(2048), dim3(256), 0, stream,
                       seg, logits, y, wt, ws);
    hipLaunchKernelGGL(finalize_k, dim3(1), dim3(64), 0, stream, ws, calib, wt, out);
}

// Round 3
// 165.365 us; speedup vs baseline: 1.1510x; 1.1510x over previous
//
#include <hip/hip_runtime.h>
#include <math.h>

// Problem geometry: seg_out/logits (2,4,128,128,128) f32, y (2,1,128,128,128) i32,
// calib (20,4) f32, weight scalar int. Output: 1 f32 scalar.
#define VB 2097152            // voxels per (batch, channel) = 128^3
#define QB (VB / 4)           // float4 quads per (batch, channel)
#define NBINS 20

// Workspace layout (as 32-bit words):
//   [0..39]    float acc[2][5][4]  : b, quantity {Sp, Spt1, Cnt1, St2, Spt2}, channel
//   [40..119]  uint  bins[2][2][20]: class (1,2), kind {true, total}, bin
#define WS_WORDS 120

// Privatized LDS histogram: 32 copies, stride 81 words (81%32=17, odd =>
// for a fixed bin the 32 copies sit on distinct banks; copy = lane&31 =>
// at most 2 lanes/copy in a wave; 2-way aliasing is free on gfx950).
#define HCOPIES 32
#define HSTRIDE 81

// 1024 blocks: 512 per batch, each thread does exactly 4 q-iterations.
#define NBLK 1024
#define BPB  512                      // blocks per batch
#define QSTRIDE (BPB * 256)           // 131072; 4 * QSTRIDE == QB
#define KITER 4

__global__ void __launch_bounds__(256, 4) hybrid_main_k(
        const float* __restrict__ seg, const float* __restrict__ logits,
        const int* __restrict__ y, const int* __restrict__ wt,
        float* __restrict__ ws)
{
    const int b   = blockIdx.x & 1;       // interleave batches across XCDs
    const int blk = blockIdx.x >> 1;      // 0..511
    const int tid = threadIdx.x;

    __shared__ unsigned int shb[HCOPIES * HSTRIDE];   // 10368 B
    __shared__ float shred[20][4];

    for (int i = tid; i < HCOPIES * HSTRIDE; i += 256) shb[i] = 0u;
    __syncthreads();

    // weight==1 => (1-w)*L2 == 0 exactly; skip the logits stream (uniform,
    // deterministic branch: inputs are restored before every launch).
    const bool need2 = (wt[0] != 1);

    const float4* s0 = (const float4*)seg + (size_t)(b * 4 + 0) * QB;
    const float4* s1 = (const float4*)seg + (size_t)(b * 4 + 1) * QB;
    const float4* s2 = (const float4*)seg + (size_t)(b * 4 + 2) * QB;
    const float4* s3 = (const float4*)seg + (size_t)(b * 4 + 3) * QB;
    const int4*   yq = (const int4*)y + (size_t)b * QB;

    // ---- Phase 1: issue ALL loads up front (memory ILP; one wait) ----
    const int q0 = blk * 256 + tid;
    float4 P0[KITER], P1[KITER], P2[KITER], P3[KITER];
    int4   Yv[KITER];
    #pragma unroll
    for (int k = 0; k < KITER; ++k) {
        const int q = q0 + k * QSTRIDE;
        P0[k] = s0[q]; P1[k] = s1[q]; P2[k] = s2[q]; P3[k] = s3[q];
        Yv[k] = yq[q];
    }

    // acc: [0..3]=Sp, [4..7]=Spt1 (one-hot), [8..11]=St2, [12..15]=Spt2
    float acc[16];
    #pragma unroll
    for (int k = 0; k < 16; ++k) acc[k] = 0.0f;
    int cnt1 = 0, cnt2 = 0, cnt3 = 0;    // cnt0 derived: 4*KITER - cnt1-cnt2-cnt3

    const float INV_STEP = 20.0f / (1.0f + 1e-8f);
    const int hbase = (tid & 31) * HSTRIDE;

    // ---- Phase 2: process ----
    #pragma unroll
    for (int k = 0; k < KITER; ++k) {
        const float pv0a[4] = {P0[k].x, P0[k].y, P0[k].z, P0[k].w};
        const float pv1a[4] = {P1[k].x, P1[k].y, P1[k].z, P1[k].w};
        const float pv2a[4] = {P2[k].x, P2[k].y, P2[k].z, P2[k].w};
        const float pv3a[4] = {P3[k].x, P3[k].y, P3[k].z, P3[k].w};
        const int   yja[4]  = {Yv[k].x, Yv[k].y, Yv[k].z, Yv[k].w};

        float4 G0, G1, G2, G3;
        if (need2) {
            const float4* l0 = (const float4*)logits + (size_t)(b * 4 + 0) * QB;
            const float4* l1 = (const float4*)logits + (size_t)(b * 4 + 1) * QB;
            const float4* l2 = (const float4*)logits + (size_t)(b * 4 + 2) * QB;
            const float4* l3 = (const float4*)logits + (size_t)(b * 4 + 3) * QB;
            const int q = q0 + k * QSTRIDE;
            G0 = l0[q]; G1 = l1[q]; G2 = l2[q]; G3 = l3[q];
        }

        #pragma unroll
        for (int j = 0; j < 4; ++j) {
            const float pv0 = pv0a[j], pv1 = pv1a[j], pv2 = pv2a[j], pv3 = pv3a[j];
            const int yj = yja[j];

            acc[0] += pv0; acc[1] += pv1; acc[2] += pv2; acc[3] += pv3;
            acc[4] += (yj == 0) ? pv0 : 0.0f;
            acc[5] += (yj == 1) ? pv1 : 0.0f;
            acc[6] += (yj == 2) ? pv2 : 0.0f;
            acc[7] += (yj == 3) ? pv3 : 0.0f;
            cnt1 += (yj == 1); cnt2 += (yj == 2); cnt3 += (yj == 3);

            if (need2) {
                const float gv[4] = {j==0?G0.x:(j==1?G0.y:(j==2?G0.z:G0.w)),
                                     j==0?G1.x:(j==1?G1.y:(j==2?G1.z:G1.w)),
                                     j==0?G2.x:(j==1?G2.y:(j==2?G2.z:G2.w)),
                                     j==0?G3.x:(j==1?G3.y:(j==2?G3.z:G3.w))};
                const float sg0 = __fdividef(1.0f, 1.0f + __expf(-gv[0]));
                const float sg1 = __fdividef(1.0f, 1.0f + __expf(-gv[1]));
                const float sg2 = __fdividef(1.0f, 1.0f + __expf(-gv[2]));
                const float sg3 = __fdividef(1.0f, 1.0f + __expf(-gv[3]));
                acc[8] += sg0; acc[9] += sg1; acc[10] += sg2; acc[11] += sg3;
                acc[12] += pv0 * sg0; acc[13] += pv1 * sg1;
                acc[14] += pv2 * sg2; acc[15] += pv3 * sg3;
            }

            // softmax ratios; inputs in [0,1) so no max-subtraction needed
            // (exp can't overflow; ratio mathematically identical).
            const float e0 = __expf(pv0), e1 = __expf(pv1);
            const float e2 = __expf(pv2), e3 = __expf(pv3);
            const float rinv = __frcp_rn((e0 + e1) + (e2 + e3));
            int b1 = (int)(e1 * rinv * INV_STEP); b1 = min(b1, 19);
            int b2 = (int)(e2 * rinv * INV_STEP); b2 = min(b2, 19);
            atomicAdd(&shb[hbase + 20 + b1], 1u);   // class-1 total
            atomicAdd(&shb[hbase + 60 + b2], 1u);   // class-2 total
            // class-1 true (yj==1) and class-2 true (yj==2) are mutually
            // exclusive -> one predicated atomic.
            if (yj == 1 || yj == 2) {
                const int addr = (yj == 1) ? (hbase + b1) : (hbase + 40 + b2);
                atomicAdd(&shb[addr], 1u);
            }
        }
    }

    // wave(64) shuffle reduce
    float fcnt1, fcnt2, fcnt3;
    {
        int c1 = cnt1, c2 = cnt2, c3 = cnt3;
        #pragma unroll
        for (int off = 32; off > 0; off >>= 1) {
            c1 += __shfl_xor(c1, off, 64);
            c2 += __shfl_xor(c2, off, 64);
            c3 += __shfl_xor(c3, off, 64);
        }
        fcnt1 = (float)c1; fcnt2 = (float)c2; fcnt3 = (float)c3;
    }
    #pragma unroll
    for (int k = 0; k < 16; ++k) {
        float v = acc[k];
        #pragma unroll
        for (int off = 32; off > 0; off >>= 1) v += __shfl_xor(v, off, 64);
        acc[k] = v;
    }
    const int wave = tid >> 6, lane = tid & 63;
    if (lane == 0) {
        // shred rows: 0..3 Sp, 4..7 Spt1, 8..11 Cnt, 12..15 St2, 16..19 Spt2
        #pragma unroll
        for (int k = 0; k < 8; ++k) shred[k][wave] = acc[k];
        const float wcnt0 = 64.0f * 4.0f * KITER - fcnt1 - fcnt2 - fcnt3;
        shred[8][wave] = wcnt0; shred[9][wave] = fcnt1;
        shred[10][wave] = fcnt2; shred[11][wave] = fcnt3;
        #pragma unroll
        for (int k = 8; k < 16; ++k) shred[k + 4][wave] = acc[k];
    }
    __syncthreads();
    if (tid < 20) {
        float t = shred[tid][0] + shred[tid][1] + shred[tid][2] + shred[tid][3];
        atomicAdd(&ws[b * 20 + tid], t);
    }
    if (tid < 80) {
        unsigned int v = 0;
        #pragma unroll
        for (int c = 0; c < HCOPIES; ++c) v += shb[c * HSTRIDE + tid];
        if (v) atomicAdd((unsigned int*)ws + 40 + tid, v);
    }
}

__device__ __forceinline__ float fsigmoid(float x) {
    return __fdividef(1.0f, 1.0f + __expf(-x));
}

__device__ double dice_term(const double Sp[2], const double St[2], const double Spt[2],
                            double w0, double w1)
{
    const double sumP = Sp[0] + Sp[1], sumT = St[0] + St[1];
    const double u1 = sumP + sumT;
    const double u0 = (2.0 * (double)VB - sumP) + (2.0 * (double)VB - sumT);
    const double uni = w0 * u0 + w1 * u1;
    double dsum = 0.0;
    for (int b = 0; b < 2; ++b) {
        const double i1 = Spt[b];
        const double i0 = (double)VB - Sp[b] - St[b] + Spt[b];
        const double inter = w0 * i0 + w1 * i1;
        double dice = (2.0 * inter + 1.0) / (uni + 1.0);
        if (isnan(dice)) dice = 1.0;
        dsum += dice;
    }
    return 1.0 - 0.5 * dsum;
}

__global__ void finalize_k(const float* __restrict__ ws,
                           const float* __restrict__ calib,
                           const int* __restrict__ wt,
                           float* __restrict__ out)
{
    const int t = threadIdx.x;

    // ECE terms in parallel: lanes 0..39 each handle one (class, bin) cell.
    const unsigned int* bins = (const unsigned int*)ws + 40;
    float term = 0.0f;
    if (t < 40) {
        const int cc = t / NBINS;        // 0 -> class 1, 1 -> class 2
        const int k  = t % NBINS;
        const float bt   = fsigmoid((float)bins[cc * 40 + k]);
        const float btot = fsigmoid((float)bins[cc * 40 + 20 + k]);
        const float cal  = fsigmoid(calib[k * 4 + (cc + 1)]);
        const float d = cal - __fdividef(bt, btot);
        term = d * d;
    }
    #pragma unroll
    for (int off = 32; off > 0; off >>= 1) term += __shfl_xor(term, off, 64);

    if (t == 0) {
        const double means[4] = {0.03, 0.02, 0.01, 0.01};
        double L1 = 0.0, L2 = 0.0;
        for (int c = 0; c < 4; ++c) {
            const double mean = means[c];
            const double w1 = 1.0 / (mean * mean);
            const double w0 = 1.0 / ((1.0 - mean) * (1.0 - mean));
            double Sp[2], Spt1[2], C1[2], St2[2], Spt2[2];
            for (int b = 0; b < 2; ++b) {
                Sp[b]   = (double)ws[b * 20 + 0 + c];
                Spt1[b] = (double)ws[b * 20 + 4 + c];
                C1[b]   = (double)ws[b * 20 + 8 + c];
                St2[b]  = (double)ws[b * 20 + 12 + c];
                Spt2[b] = (double)ws[b * 20 + 16 + c];
            }
            L1 += dice_term(Sp, C1, Spt1, w0, w1);
            L2 += dice_term(Sp, St2, Spt2, w0, w1);
        }
        L1 *= 0.2; L2 *= 0.2;   // sum of 4 channel losses / 5.0
        const double w = (double)wt[0];
        const double ece = (double)term / (double)NBINS;
        out[0] = (float)(w * L1 + (1.0 - w) * L2 + ece);
    }
}

extern "C" void kernel_launch(void* const* d_in, const int* in_sizes, int n_in,
                              void* d_out, int out_size, void* d_ws, size_t ws_size,
                              hipStream_t stream)
{
    const float* seg    = (const float*)d_in[0];
    const float* calib  = (const float*)d_in[1];
    const float* logits = (const float*)d_in[2];
    const int*   y      = (const int*)d_in[3];
    const int*   wt     = (const int*)d_in[4];
    float* ws  = (float*)d_ws;
    float* out = (float*)d_out;

    hipMemsetAsync(ws, 0, WS_WORDS * sizeof(float), stream);
    hipLaunchKernelGGL(hybrid_main_k, dim3(NBLK), dim3(256), 0, stream,
                       seg, logits, y, wt, ws);
    hipLaunchKernelGGL(finalize_k, dim3(1), dim3(64), 0, stream, ws, calib, wt, out);
}